// Round 3
// baseline (81.509 us; speedup 1.0000x reference)
//
#include <hip/hip_runtime.h>
#include <math.h>

// out[b,oc,y,x] = max_{dy,dx} min(xmax[b, y+dy-2, x+dx-2], k[oc,dy,dx])
// xmax = max over C=32 input channels; OOB patch values = -inf.
// Shapes: x (16,32,256,256) f32, k (32,5,5) f32, out (16,32,256,256) f32.

#define BATCH 16
#define CH    32
#define OCH   32
#define HH    256
#define WW    256
#define HWSZ  (HH * WW)          // 65536

// ---------------- Pass 1: channel max, float4 vectorized ----------------
__global__ __launch_bounds__(256) void chanmax_kernel(const float* __restrict__ x,
                                                      float* __restrict__ xm) {
    int i4 = blockIdx.x * blockDim.x + threadIdx.x;   // 0 .. 262143
    int b  = i4 >> 14;
    int r  = i4 & 16383;
    const float4* base = (const float4*)x + (size_t)b * CH * (HWSZ / 4) + r;
    float4 m = base[0];
#pragma unroll
    for (int c = 1; c < CH; ++c) {
        float4 v = base[(size_t)c * (HWSZ / 4)];
        m.x = fmaxf(m.x, v.x);
        m.y = fmaxf(m.y, v.y);
        m.z = fmaxf(m.z, v.z);
        m.w = fmaxf(m.w, v.w);
    }
    ((float4*)xm)[i4] = m;
}

// ---------------- Pass 2: 5x5 maxmin "conv" ----------------
// One thread = 4 consecutive x positions x 8 output channels (oc-split 4).
// Kernel taps staged in LDS (uniform-address broadcast reads per oc).
// Patch loaded as 3 aligned float4 per row; 25 v_min + 12 v_max3 per px/oc.
__device__ __forceinline__ float vmax3(float a, float b, float c) {
    float d;
    asm("v_max3_f32 %0, %1, %2, %3" : "=v"(d) : "v"(a), "v"(b), "v"(c));
    return d;
}

__global__ __launch_bounds__(256) void maxmin_conv_kernel(const float* __restrict__ xm,
                                                          const float* __restrict__ kk,
                                                          float* __restrict__ out) {
    __shared__ float lk[8 * 25];                      // this block's 8-oc tap slice
    int bid = blockIdx.x;
    int q   = bid & 3;                                // oc group: q*8 .. q*8+7
    int t   = (bid >> 2) * blockDim.x + threadIdx.x;  // 0 .. 262143
    if (threadIdx.x < 200) lk[threadIdx.x] = kk[q * 200 + threadIdx.x];
    __syncthreads();

    int x0 = (t & 63) << 2;                           // 0,4,...,252
    int y  = (t >> 6) & 255;
    int b  = t >> 14;

    const float NI = -INFINITY;
    bool xlo = (x0 == 0);
    bool xhi = (x0 == 252);
    int fi = x0 >> 2;
    int f0 = fi - 1; if (f0 < 0)  f0 = 0;             // clamped; garbage masked by xlo
    int f2 = fi + 1; if (f2 > 63) f2 = 63;            // clamped; garbage masked by xhi

    // 5x8 patch in registers via 3 float4 loads per row.
    float p[40];
#pragma unroll
    for (int dy = 0; dy < 5; ++dy) {
        int yy  = y + dy - 2;
        bool rv = (yy >= 0) && (yy < HH);
        int yc  = yy < 0 ? 0 : (yy > HH - 1 ? HH - 1 : yy);
        const float4* row = (const float4*)(xm + ((size_t)b * HH + yc) * WW);
        float4 A = row[f0];
        float4 B = row[fi];
        float4 C = row[f2];
        float* pr = p + dy * 8;
        pr[0] = (rv && !xlo) ? A.z : NI;
        pr[1] = (rv && !xlo) ? A.w : NI;
        pr[2] = rv ? B.x : NI;
        pr[3] = rv ? B.y : NI;
        pr[4] = rv ? B.z : NI;
        pr[5] = rv ? B.w : NI;
        pr[6] = (rv && !xhi) ? C.x : NI;
        pr[7] = (rv && !xhi) ? C.y : NI;
    }

    size_t obase = (size_t)b * OCH * HWSZ + (size_t)(q * 8) * HWSZ
                 + (size_t)y * WW + x0;

#pragma unroll 2
    for (int o = 0; o < 8; ++o) {
        const float* kv = lk + o * 25;
        float kr[25];
#pragma unroll
        for (int i = 0; i < 25; ++i) kr[i] = kv[i];   // uniform addr -> LDS broadcast

        float a[4];
#pragma unroll
        for (int j = 0; j < 4; ++j) {
            float m[25];
#pragma unroll
            for (int dy = 0; dy < 5; ++dy)
#pragma unroll
                for (int dx = 0; dx < 5; ++dx)
                    m[dy * 5 + dx] = fminf(p[dy * 8 + dx + j], kr[dy * 5 + dx]);
            float t0 = vmax3(m[0],  m[1],  m[2]);
            float t1 = vmax3(m[3],  m[4],  m[5]);
            float t2 = vmax3(m[6],  m[7],  m[8]);
            float t3 = vmax3(m[9],  m[10], m[11]);
            float t4 = vmax3(m[12], m[13], m[14]);
            float t5 = vmax3(m[15], m[16], m[17]);
            float t6 = vmax3(m[18], m[19], m[20]);
            float t7 = vmax3(m[21], m[22], m[23]);
            float u0 = vmax3(t0, t1, t2);
            float u1 = vmax3(t3, t4, t5);
            float u2 = vmax3(t6, t7, m[24]);
            a[j] = vmax3(u0, u1, u2);
        }
        *(float4*)(out + obase + (size_t)o * HWSZ) = make_float4(a[0], a[1], a[2], a[3]);
    }
}

extern "C" void kernel_launch(void* const* d_in, const int* in_sizes, int n_in,
                              void* d_out, int out_size, void* d_ws, size_t ws_size,
                              hipStream_t stream) {
    const float* x  = (const float*)d_in[0];
    const float* kk = (const float*)d_in[1];
    float* out      = (float*)d_out;
    float* xm       = (float*)d_ws;   // 16*256*256*4 = 4 MB scratch

    chanmax_kernel<<<BATCH * HWSZ / 4 / 256, 256, 0, stream>>>(x, xm);
    maxmin_conv_kernel<<<4 * BATCH * HWSZ / 4 / 256, 256, 0, stream>>>(xm, kk, out);
}

// Round 4
// 80.683 us; speedup vs baseline: 1.0102x; 1.0102x over previous
//
#include <hip/hip_runtime.h>
#include <math.h>

// out[b,oc,y,x] = max_{dy,dx} min(xmax[b, y+dy-2, x+dx-2], k[oc,dy,dx])
// xmax = max over C=32 input channels; OOB patch values = -inf.
// Shapes: x (16,32,256,256) f32, k (32,5,5) f32, out (16,32,256,256) f32.

#define BATCH 16
#define CH    32
#define OCH   32
#define HH    256
#define WW    256
#define HWSZ  (HH * WW)          // 65536

// ---------------- Pass 1: channel max ----------------
// Explicit 16-deep load batches: 16 outstanding global_load_dwordx4 per wave
// before the first dependent use (Little's law: need >~10KB in flight per CU
// to hit 7 TB/s; serialized load->max chains collapse BW).
__global__ __launch_bounds__(256) void chanmax_kernel(const float* __restrict__ x,
                                                      float* __restrict__ xm) {
    int i4 = blockIdx.x * blockDim.x + threadIdx.x;   // 0 .. 262143
    int b  = i4 >> 14;
    int r  = i4 & 16383;
    const float4* base = (const float4*)x + (size_t)b * (CH * (HWSZ / 4)) + r;

    float4 v[16];
#pragma unroll
    for (int j = 0; j < 16; ++j) v[j] = base[(size_t)j * (HWSZ / 4)];
    float4 m = v[0];
#pragma unroll
    for (int j = 1; j < 16; ++j) {
        m.x = fmaxf(m.x, v[j].x);
        m.y = fmaxf(m.y, v[j].y);
        m.z = fmaxf(m.z, v[j].z);
        m.w = fmaxf(m.w, v[j].w);
    }
#pragma unroll
    for (int j = 0; j < 16; ++j) v[j] = base[(size_t)(16 + j) * (HWSZ / 4)];
#pragma unroll
    for (int j = 0; j < 16; ++j) {
        m.x = fmaxf(m.x, v[j].x);
        m.y = fmaxf(m.y, v[j].y);
        m.z = fmaxf(m.z, v[j].z);
        m.w = fmaxf(m.w, v[j].w);
    }
    ((float4*)xm)[i4] = m;
}

// ---------------- Pass 2: 5x5 maxmin "conv" ----------------
__device__ __forceinline__ float vmax3(float a, float b, float c) {
    float d;
    asm("v_max3_f32 %0, %1, %2, %3" : "=v"(d) : "v"(a), "v"(b), "v"(c));
    return d;
}

__global__ __launch_bounds__(256) void maxmin_conv_kernel(const float* __restrict__ xm,
                                                          const float* __restrict__ kk,
                                                          float* __restrict__ out) {
    __shared__ float lk[8][28];                       // 28-padded so rows are 16B-aligned
    int bid = blockIdx.x;
    int q   = bid & 3;                                // oc group: q*8 .. q*8+7
    int t   = (bid >> 2) * blockDim.x + threadIdx.x;  // 0 .. 262143
    if (threadIdx.x < 200) lk[threadIdx.x / 25][threadIdx.x % 25] = kk[q * 200 + threadIdx.x];
    __syncthreads();

    int x0 = (t & 63) << 2;                           // 0,4,...,252
    int y  = (t >> 6) & 255;
    int b  = t >> 14;

    const float NI = -INFINITY;
    bool xlo = (x0 == 0);
    bool xhi = (x0 == 252);
    int fi = x0 >> 2;
    int f0 = fi - 1; if (f0 < 0)  f0 = 0;             // clamped; masked by xlo
    int f2 = fi + 1; if (f2 > 63) f2 = 63;            // clamped; masked by xhi

    // Issue all 15 patch float4 loads as one burst, then select.
    float4 A[5], Bv[5], Cv[5];
    int yc[5];
    bool rvv[5];
#pragma unroll
    for (int dy = 0; dy < 5; ++dy) {
        int yy  = y + dy - 2;
        rvv[dy] = (yy >= 0) && (yy < HH);
        yc[dy]  = yy < 0 ? 0 : (yy > HH - 1 ? HH - 1 : yy);
    }
#pragma unroll
    for (int dy = 0; dy < 5; ++dy) {
        const float4* row = (const float4*)(xm + ((size_t)b * HH + yc[dy]) * WW);
        A[dy]  = row[f0];
        Bv[dy] = row[fi];
        Cv[dy] = row[f2];
    }

    float p[40];
#pragma unroll
    for (int dy = 0; dy < 5; ++dy) {
        bool rv = rvv[dy];
        float* pr = p + dy * 8;
        pr[0] = (rv && !xlo) ? A[dy].z  : NI;
        pr[1] = (rv && !xlo) ? A[dy].w  : NI;
        pr[2] = rv ? Bv[dy].x : NI;
        pr[3] = rv ? Bv[dy].y : NI;
        pr[4] = rv ? Bv[dy].z : NI;
        pr[5] = rv ? Bv[dy].w : NI;
        pr[6] = (rv && !xhi) ? Cv[dy].x : NI;
        pr[7] = (rv && !xhi) ? Cv[dy].y : NI;
    }

    size_t obase = (size_t)b * OCH * HWSZ + (size_t)(q * 8) * HWSZ
                 + (size_t)y * WW + x0;

#pragma unroll 2
    for (int o = 0; o < 8; ++o) {
        // taps via 7 vector LDS reads (uniform address -> broadcast)
        float4 k0 = *(const float4*)&lk[o][0];
        float4 k1 = *(const float4*)&lk[o][4];
        float4 k2 = *(const float4*)&lk[o][8];
        float4 k3 = *(const float4*)&lk[o][12];
        float4 k4 = *(const float4*)&lk[o][16];
        float4 k5 = *(const float4*)&lk[o][20];
        float  k6 = lk[o][24];
        float kr[25] = { k0.x,k0.y,k0.z,k0.w, k1.x,k1.y,k1.z,k1.w,
                         k2.x,k2.y,k2.z,k2.w, k3.x,k3.y,k3.z,k3.w,
                         k4.x,k4.y,k4.z,k4.w, k5.x,k5.y,k5.z,k5.w, k6 };

        float a[4];
#pragma unroll
        for (int j = 0; j < 4; ++j) {
            float m[25];
#pragma unroll
            for (int dy = 0; dy < 5; ++dy)
#pragma unroll
                for (int dx = 0; dx < 5; ++dx)
                    m[dy * 5 + dx] = fminf(p[dy * 8 + dx + j], kr[dy * 5 + dx]);
            float t0 = vmax3(m[0],  m[1],  m[2]);
            float t1 = vmax3(m[3],  m[4],  m[5]);
            float t2 = vmax3(m[6],  m[7],  m[8]);
            float t3 = vmax3(m[9],  m[10], m[11]);
            float t4 = vmax3(m[12], m[13], m[14]);
            float t5 = vmax3(m[15], m[16], m[17]);
            float t6 = vmax3(m[18], m[19], m[20]);
            float t7 = vmax3(m[21], m[22], m[23]);
            float u0 = vmax3(t0, t1, t2);
            float u1 = vmax3(t3, t4, t5);
            float u2 = vmax3(t6, t7, m[24]);
            a[j] = vmax3(u0, u1, u2);
        }
        *(float4*)(out + obase + (size_t)o * HWSZ) = make_float4(a[0], a[1], a[2], a[3]);
    }
}

extern "C" void kernel_launch(void* const* d_in, const int* in_sizes, int n_in,
                              void* d_out, int out_size, void* d_ws, size_t ws_size,
                              hipStream_t stream) {
    const float* x  = (const float*)d_in[0];
    const float* kk = (const float*)d_in[1];
    float* out      = (float*)d_out;
    float* xm       = (float*)d_ws;   // 16*256*256*4 = 4 MB scratch

    chanmax_kernel<<<BATCH * HWSZ / 4 / 256, 256, 0, stream>>>(x, xm);
    maxmin_conv_kernel<<<4 * BATCH * HWSZ / 4 / 256, 256, 0, stream>>>(xm, kk, out);
}

// Round 5
// 66.101 us; speedup vs baseline: 1.2331x; 1.2206x over previous
//
#include <hip/hip_runtime.h>
#include <math.h>

// Fused: out[b,oc,y,x] = max_{dy,dx} min(xmax[b,y+dy-2,x+dx-2], k[oc,dy,dx])
// xmax = max over C=32 channels; OOB = -inf.
// x (16,32,256,256) f32, k (32,5,5) f32, out (16,32,256,256) f32.
// One block = one 32x32 output tile (all 32 oc). Phase 1: channel-max of the
// 36x40 halo tile into LDS (-inf borders). Phase 2: sliding-window conv.

#define BATCH 16
#define CH    32
#define OCH   32
#define HH    256
#define WW    256
#define HWSZ  (HH * WW)
#define TW    32
#define TH    32
#define LW    40              // tile width in floats (10 float4), origin x0-4
#define LH    36              // tile height in rows, origin y0-2
#define NWG   (BATCH * (WW / TW) * (HH / TH))   // 1024

__device__ __forceinline__ float vmax3(float a, float b, float c) {
    float d;
    asm("v_max3_f32 %0, %1, %2, %3" : "=v"(d) : "v"(a), "v"(b), "v"(c));
    return d;
}

__global__ __launch_bounds__(256, 3) void fused_maxmin_kernel(const float* __restrict__ x,
                                                              const float* __restrict__ kk,
                                                              float* __restrict__ out) {
    __shared__ float xmt[LH][LW];      // channel-max halo tile, -inf at OOB
    __shared__ float lkf[OCH * 25];    // all taps

    int tid = threadIdx.x;
    int bid = blockIdx.x;
    // XCD-chunked swizzle (1024 % 8 == 0 -> bijective): consecutive tiles on one XCD.
    int swz = (bid & 7) * (NWG >> 3) + (bid >> 3);
    int b   = swz >> 6;            // batch
    int ty  = (swz >> 3) & 7;      // tile row
    int tx  = swz & 7;             // tile col

    for (int i = tid; i < OCH * 25; i += 256) lkf[i] = kk[i];

    const float NI = -INFINITY;
    int x4base = tx * (TW / 4) - 1;    // first float4 col (global), = (x0-4)/4
    int ybase  = ty * TH - 2;          // first row (global), = y0-2
    const float4* xb = (const float4*)(x + (size_t)b * CH * HWSZ);

    // ---- Phase 1: channel max into LDS (360 float4 positions) ----
    for (int p = tid; p < (LW / 4) * LH; p += 256) {
        int pc = p % (LW / 4);
        int pr = p / (LW / 4);
        int c4 = x4base + pc;
        int rw = ybase + pr;
        bool valid = (c4 >= 0) && (c4 < WW / 4) && (rw >= 0) && (rw < HH);
        int c4c = c4 < 0 ? 0 : (c4 > WW / 4 - 1 ? WW / 4 - 1 : c4);
        int rwc = rw < 0 ? 0 : (rw > HH - 1 ? HH - 1 : rw);
        const float4* src = xb + (size_t)rwc * (WW / 4) + c4c;
        float4 m = src[0];
#pragma unroll
        for (int c = 1; c < CH; ++c) {
            float4 v = src[(size_t)c * (HWSZ / 4)];
            m.x = fmaxf(m.x, v.x);
            m.y = fmaxf(m.y, v.y);
            m.z = fmaxf(m.z, v.z);
            m.w = fmaxf(m.w, v.w);
        }
        if (!valid) { m.x = NI; m.y = NI; m.z = NI; m.w = NI; }
        *(float4*)&xmt[pr][pc * 4] = m;
    }
    __syncthreads();

    // ---- Phase 2: conv. thread = (xg: 4 px, yg: 8 rows, og: 4 oc) ----
    int xg = tid & 7;                  // 8 x-groups * 4 px = 32
    int yg = (tid >> 3) & 3;           // 4 y-groups * 8 rows = 32
    int og = tid >> 5;                 // 8 oc-groups * 4 oc = 32
    int orow0 = yg * 8;

    const float* wbase = &xmt[0][4 * xg];   // aligned: patch quads at +0,+16,+32 B

    for (int oi = 0; oi < 4; ++oi) {
        int o = og * 4 + oi;
        float kr[25];
#pragma unroll
        for (int i = 0; i < 25; ++i) kr[i] = lkf[o * 25 + i];

        // 5-row circular window, 12 floats wide (3 aligned float4).
        float w[5][12];
#pragma unroll
        for (int r = 0; r < 4; ++r)
#pragma unroll
            for (int q = 0; q < 3; ++q)
                *(float4*)&w[r][4 * q] = *(const float4*)(wbase + (orow0 + r) * LW + 4 * q);

        float* op = out + (size_t)(b * OCH + o) * HWSZ
                  + (size_t)(ty * TH + orow0) * WW + tx * TW + 4 * xg;

#pragma unroll
        for (int r = 0; r < 8; ++r) {
            int wl = (r + 4) % 5;          // slot for new row (tile row orow0+r+4)
#pragma unroll
            for (int q = 0; q < 3; ++q)
                *(float4*)&w[wl][4 * q] = *(const float4*)(wbase + (orow0 + r + 4) * LW + 4 * q);

            float a[4];
#pragma unroll
            for (int j = 0; j < 4; ++j) {
                float m[25];
#pragma unroll
                for (int dy = 0; dy < 5; ++dy) {
                    int wr = (r + dy) % 5; // tile row orow0+r+dy
#pragma unroll
                    for (int dx = 0; dx < 5; ++dx)
                        m[dy * 5 + dx] = fminf(w[wr][j + dx + 2], kr[dy * 5 + dx]);
                }
                float t0 = vmax3(m[0],  m[1],  m[2]);
                float t1 = vmax3(m[3],  m[4],  m[5]);
                float t2 = vmax3(m[6],  m[7],  m[8]);
                float t3 = vmax3(m[9],  m[10], m[11]);
                float t4 = vmax3(m[12], m[13], m[14]);
                float t5 = vmax3(m[15], m[16], m[17]);
                float t6 = vmax3(m[18], m[19], m[20]);
                float t7 = vmax3(m[21], m[22], m[23]);
                float u0 = vmax3(t0, t1, t2);
                float u1 = vmax3(t3, t4, t5);
                float u2 = vmax3(t6, t7, m[24]);
                a[j] = vmax3(u0, u1, u2);
            }
            *(float4*)(op + (size_t)r * WW) = make_float4(a[0], a[1], a[2], a[3]);
        }
    }
}

extern "C" void kernel_launch(void* const* d_in, const int* in_sizes, int n_in,
                              void* d_out, int out_size, void* d_ws, size_t ws_size,
                              hipStream_t stream) {
    const float* x  = (const float*)d_in[0];
    const float* kk = (const float*)d_in[1];
    float* out      = (float*)d_out;
    fused_maxmin_kernel<<<NWG, 256, 0, stream>>>(x, kk, out);
}